// Round 3
// baseline (34.731 us; speedup 1.0000x reference)
//
#include <hip/hip_runtime.h>

// Problem constants (from reference: x = [8, 192, 64, 64] fp32)
#define BB 8
#define CC 192
#define HWN 4096            // 64*64
// scale^2 = (c^-0.25)^2 = c^-0.5 = 1/sqrt(192)
#define SCALE2 0.07216878364870323f

// ---------------------------------------------------------------------------
// Kernel A: per-(b,c) mean over the 4096 spatial positions.
// grid = B*C blocks, 256 threads. Each thread reads 4 float4 (16 floats).
__global__ void mean_kernel(const float* __restrict__ x, float* __restrict__ m) {
    int bc = blockIdx.x;                       // 0 .. B*C-1
    int t  = threadIdx.x;
    const float4* p4 = (const float4*)(x + (size_t)bc * HWN);
    float s = 0.f;
#pragma unroll
    for (int i = 0; i < 4; ++i) {
        float4 v = p4[t + i * 256];
        s += v.x + v.y + v.z + v.w;
    }
    for (int off = 32; off; off >>= 1) s += __shfl_down(s, off);
    __shared__ float sm[4];
    int wave = t >> 6, lane = t & 63;
    if (lane == 0) sm[wave] = s;
    __syncthreads();
    if (t == 0) m[bc] = (sm[0] + sm[1] + sm[2] + sm[3]) * (1.0f / HWN);
}

// ---------------------------------------------------------------------------
// Kernel B: spatial scores. scores[b][s] = SCALE2 * sum_c m[b,c] * x[b,c,s]
// grid = (HWN/256, B), 256 threads. Lane -> spatial s (coalesced); loop c.
__global__ void score_kernel(const float* __restrict__ x,
                             const float* __restrict__ m,
                             float* __restrict__ scores) {
    int b = blockIdx.y;
    int s = blockIdx.x * 256 + threadIdx.x;
    __shared__ float ml[CC];
    if (threadIdx.x < CC) ml[threadIdx.x] = m[b * CC + threadIdx.x];
    __syncthreads();
    const float* p = x + (size_t)b * CC * HWN + s;
    float acc = 0.f;
#pragma unroll 8
    for (int c = 0; c < CC; ++c) acc += ml[c] * p[(size_t)c * HWN];
    scores[b * HWN + s] = acc * SCALE2;
}

// ---------------------------------------------------------------------------
// Kernel C: per-batch softmax over T = HWN+1 values (score0 computed here).
// In-place: scores[b][*] becomes the spatial weights; w0[b] the mean-token w.
// grid = B blocks, 256 threads.
__global__ void softmax_kernel(const float* __restrict__ m,
                               float* __restrict__ scores,
                               float* __restrict__ w0) {
    int b = blockIdx.x;
    int t = threadIdx.x;
    int wave = t >> 6, lane = t & 63;
    __shared__ float red[4];
    __shared__ float sh_scalar;

    // score0 = SCALE2 * ||m_b||^2   (C=192 < 256 threads)
    float q = (t < CC) ? m[b * CC + t] : 0.f;
    float p0 = q * q;
    for (int off = 32; off; off >>= 1) p0 += __shfl_down(p0, off);
    if (lane == 0) red[wave] = p0;
    __syncthreads();
    if (t == 0) sh_scalar = (red[0] + red[1] + red[2] + red[3]) * SCALE2;
    __syncthreads();
    float score0 = sh_scalar;
    __syncthreads();

    float* sc = scores + b * HWN;

    // max over {score0, sc[0..HWN)}
    float mx = score0;
    for (int i = t; i < HWN; i += 256) mx = fmaxf(mx, sc[i]);
    for (int off = 32; off; off >>= 1) mx = fmaxf(mx, __shfl_down(mx, off));
    if (lane == 0) red[wave] = mx;
    __syncthreads();
    if (t == 0) sh_scalar = fmaxf(fmaxf(red[0], red[1]), fmaxf(red[2], red[3]));
    __syncthreads();
    mx = sh_scalar;
    __syncthreads();

    // sum of exp
    float se = (t == 0) ? __expf(score0 - mx) : 0.f;
    for (int i = t; i < HWN; i += 256) se += __expf(sc[i] - mx);
    for (int off = 32; off; off >>= 1) se += __shfl_down(se, off);
    if (lane == 0) red[wave] = se;
    __syncthreads();
    if (t == 0) sh_scalar = 1.0f / (red[0] + red[1] + red[2] + red[3]);
    __syncthreads();
    float inv = sh_scalar;

    // write normalized weights (in-place over scores)
    for (int i = t; i < HWN; i += 256) sc[i] = __expf(sc[i] - mx) * inv;
    if (t == 0) w0[b] = __expf(score0 - mx) * inv;
}

// ---------------------------------------------------------------------------
// Kernel D: out[b,c] = w0[b]*m[b,c] + sum_s w[b,s]*x[b,c,s]
// grid = B*C blocks, 256 threads, float4 loads of both x and w.
__global__ void out_kernel(const float* __restrict__ x,
                           const float* __restrict__ w,
                           const float* __restrict__ w0,
                           const float* __restrict__ m,
                           float* __restrict__ out) {
    int bc = blockIdx.x;
    int b  = bc / CC;
    int t  = threadIdx.x;
    const float4* p4 = (const float4*)(x + (size_t)bc * HWN);
    const float4* w4 = (const float4*)(w + b * HWN);
    float acc = 0.f;
#pragma unroll
    for (int i = 0; i < 4; ++i) {
        float4 v  = p4[t + i * 256];
        float4 ww = w4[t + i * 256];
        acc += v.x * ww.x + v.y * ww.y + v.z * ww.z + v.w * ww.w;
    }
    for (int off = 32; off; off >>= 1) acc += __shfl_down(acc, off);
    __shared__ float sm[4];
    int wave = t >> 6, lane = t & 63;
    if (lane == 0) sm[wave] = acc;
    __syncthreads();
    if (t == 0) out[bc] = sm[0] + sm[1] + sm[2] + sm[3] + w0[b] * m[bc];
}

// ---------------------------------------------------------------------------
extern "C" void kernel_launch(void* const* d_in, const int* in_sizes, int n_in,
                              void* d_out, int out_size, void* d_ws, size_t ws_size,
                              hipStream_t stream) {
    const float* x = (const float*)d_in[0];
    float* out = (float*)d_out;

    // workspace layout (floats):
    //   m      : B*C      = 1536        @ 0
    //   scores : B*HWN    = 32768       @ 1536   (16B aligned: 1536*4 = 6144)
    //   w0     : B        = 8           @ 34304
    float* ws     = (float*)d_ws;
    float* m      = ws;
    float* scores = ws + BB * CC;
    float* w0     = ws + BB * CC + BB * HWN;

    mean_kernel<<<BB * CC, 256, 0, stream>>>(x, m);
    score_kernel<<<dim3(HWN / 256, BB), 256, 0, stream>>>(x, m, scores);
    softmax_kernel<<<BB, 256, 0, stream>>>(m, scores, w0);
    out_kernel<<<BB * CC, 256, 0, stream>>>(x, scores, w0, m, out);
}

// Round 4
// 27.428 us; speedup vs baseline: 1.2663x; 1.2663x over previous
//
#include <hip/hip_runtime.h>

// Problem constants (from reference: x = [8, 192, 64, 64] fp32)
#define BB 8
#define CC 192
#define HWN 4096            // 64*64
// scale^2 = (c^-0.25)^2 = c^-0.5 = 1/sqrt(192)
#define SCALE2 0.07216878364870323f
#define NCHUNK 32           // score blocks per batch
#define CHUNKW 128          // threads per score block (NCHUNK*CHUNKW == HWN)

// ---------------------------------------------------------------------------
// Kernel A: per-(b,c) mean over the 4096 spatial positions.
// grid = B*C = 1536 blocks, 256 threads; 4 float4 loads per thread.
__global__ void mean_kernel(const float* __restrict__ x, float* __restrict__ m) {
    int bc = blockIdx.x;
    int t  = threadIdx.x;
    const float4* p4 = (const float4*)(x + (size_t)bc * HWN);
    float s = 0.f;
#pragma unroll
    for (int i = 0; i < 4; ++i) {
        float4 v = p4[t + i * 256];
        s += v.x + v.y + v.z + v.w;
    }
    for (int off = 32; off; off >>= 1) s += __shfl_down(s, off);
    __shared__ float sm[4];
    int wave = t >> 6, lane = t & 63;
    if (lane == 0) sm[wave] = s;
    __syncthreads();
    if (t == 0) m[bc] = (sm[0] + sm[1] + sm[2] + sm[3]) * (1.0f / HWN);
}

// ---------------------------------------------------------------------------
// Kernel B: scores[b][s] = SCALE2 * sum_c m[b,c] * x[b,c,s], PLUS per-chunk
// softmax partials (local max, local sum-of-exp). Chunk 0 additionally emits
// the mean-token score0 = SCALE2*||m_b||^2 as partial slot 0 with weight 1.
// grid = (NCHUNK, B) = (32, 8), 128 threads (one spatial position each).
__global__ void score_kernel(const float* __restrict__ x,
                             const float* __restrict__ m,
                             float* __restrict__ scores,
                             float2* __restrict__ partials) {
    int b = blockIdx.y;
    int t = threadIdx.x;                    // 0..127
    int s = blockIdx.x * CHUNKW + t;
    int wave = t >> 6, lane = t & 63;
    __shared__ float ml[CC];
    __shared__ float r2[2], r3[2], r4[2];

    for (int i = t; i < CC; i += CHUNKW) ml[i] = m[b * CC + i];
    __syncthreads();

    const float* p = x + (size_t)b * CC * HWN + s;
    float acc = 0.f;
#pragma unroll 8
    for (int c = 0; c < CC; ++c) acc += ml[c] * p[(size_t)c * HWN];
    float sc = acc * SCALE2;
    scores[b * HWN + s] = sc;

    // block max over the 128 scores
    float mx = sc;
    for (int off = 32; off; off >>= 1) mx = fmaxf(mx, __shfl_down(mx, off));
    if (lane == 0) r2[wave] = mx;
    __syncthreads();
    mx = fmaxf(r2[0], r2[1]);

    // block sum of exp
    float e = __expf(sc - mx);
    for (int off = 32; off; off >>= 1) e += __shfl_down(e, off);
    if (lane == 0) r3[wave] = e;
    __syncthreads();
    if (t == 0)
        partials[b * (NCHUNK + 1) + 1 + blockIdx.x] = make_float2(mx, r3[0] + r3[1]);

    // chunk 0: score0 partial (exp weight 1)
    if (blockIdx.x == 0) {
        float q = 0.f;
        for (int i = t; i < CC; i += CHUNKW) q += ml[i] * ml[i];
        for (int off = 32; off; off >>= 1) q += __shfl_down(q, off);
        if (lane == 0) r4[wave] = q;
        __syncthreads();
        if (t == 0)
            partials[b * (NCHUNK + 1)] = make_float2((r4[0] + r4[1]) * SCALE2, 1.0f);
    }
}

// ---------------------------------------------------------------------------
// Kernel C: out[b,c] = (sum_s exp(sc[s]-MX)*x[b,c,s]) * inv + w0*m[b,c]
// Softmax finalize (33-way LSE combine) done inline in the first wave.
// grid = B*C = 1536 blocks, 256 threads.
__global__ void out_kernel(const float* __restrict__ x,
                           const float* __restrict__ scores,
                           const float2* __restrict__ partials,
                           const float* __restrict__ m,
                           float* __restrict__ out) {
    int bc = blockIdx.x;
    int b  = bc / CC;
    int t  = threadIdx.x;
    int wave = t >> 6, lane = t & 63;
    __shared__ float sMX, sInv, sW0;
    __shared__ float sm[4];

    if (t < 64) {
        const float2* pp = partials + b * (NCHUNK + 1);
        float mxv = (t <= NCHUNK) ? pp[t].x : -3.0e38f;
        float sev = (t <= NCHUNK) ? pp[t].y : 0.f;
        float MX = mxv;
        for (int off = 32; off; off >>= 1) MX = fmaxf(MX, __shfl_down(MX, off));
        MX = __shfl(MX, 0);
        float e = sev * __expf(mxv - MX);
        for (int off = 32; off; off >>= 1) e += __shfl_down(e, off);
        if (t == 0) {
            float inv = 1.0f / e;
            sMX = MX;
            sInv = inv;
            sW0 = __expf(pp[0].x - MX) * inv;   // weight of the mean token
        }
    }
    __syncthreads();
    float MX = sMX, inv = sInv;

    const float4* p4 = (const float4*)(x + (size_t)bc * HWN);
    const float4* s4 = (const float4*)(scores + b * HWN);
    float acc = 0.f;
#pragma unroll
    for (int i = 0; i < 4; ++i) {
        float4 v  = p4[t + i * 256];
        float4 sc = s4[t + i * 256];
        acc += v.x * __expf(sc.x - MX);
        acc += v.y * __expf(sc.y - MX);
        acc += v.z * __expf(sc.z - MX);
        acc += v.w * __expf(sc.w - MX);
    }
    for (int off = 32; off; off >>= 1) acc += __shfl_down(acc, off);
    if (lane == 0) sm[wave] = acc;
    __syncthreads();
    if (t == 0) out[bc] = (sm[0] + sm[1] + sm[2] + sm[3]) * inv + sW0 * m[bc];
}

// ---------------------------------------------------------------------------
extern "C" void kernel_launch(void* const* d_in, const int* in_sizes, int n_in,
                              void* d_out, int out_size, void* d_ws, size_t ws_size,
                              hipStream_t stream) {
    const float* x = (const float*)d_in[0];
    float* out = (float*)d_out;

    // workspace layout (floats):
    //   m        : B*C   = 1536            @ 0
    //   scores   : B*HWN = 32768           @ 1536   (byte off 6144, 16B-aligned)
    //   partials : B*(NCHUNK+1) float2     @ 34304  (byte off 137216, 8B-aligned)
    float*  ws       = (float*)d_ws;
    float*  m        = ws;
    float*  scores   = ws + BB * CC;
    float2* partials = (float2*)(ws + BB * CC + BB * HWN);

    mean_kernel<<<BB * CC, 256, 0, stream>>>(x, m);
    score_kernel<<<dim3(NCHUNK, BB), CHUNKW, 0, stream>>>(x, m, scores, partials);
    out_kernel<<<BB * CC, 256, 0, stream>>>(x, scores, partials, m, out);
}